// Round 10
// baseline (471.239 us; speedup 1.0000x reference)
//
#include <hip/hip_runtime.h>
#include <hip/hip_fp16.h>
#include <hip/hip_cooperative_groups.h>

namespace cg = cooperative_groups;

typedef _Float16 f16x8 __attribute__((ext_vector_type(8)));
typedef _Float16 f16x4 __attribute__((ext_vector_type(4)));
typedef float    f32x4 __attribute__((ext_vector_type(4)));

constexpr int NN = 50000;        // nodes
constexpr int NE = 800000;       // real edges (self-loops inline in gather)
constexpr int IC = 128;          // in channels
constexpr int HC = 256;          // heads * out_ch
constexpr int OC = 64;           // out channels
constexpr int NSB = (NN + 1023) / 1024;   // 49 scan blocks
constexpr int NT  = (NN + 63) / 64;       // 782 proj tiles

// ---------------------------------------------------------------------------
// One cooperative mega-kernel. Phases separated by grid.sync():
//  A: zero deg, rowptr[NN]=NE
//  B: Wt transpose (fp16) + dst histogram
//  C: scan1 (block-local prefix over 1024-entry chunks)
//  D: apply chunk offsets (wave-reduce of bsum) -> rowptr, cursor
//  E: proj MFMA (1 tile/block) || fill CSR (grid-stride)
//  F: gather, one wave per dst node, grid-stride
// ---------------------------------------------------------------------------
__global__ __launch_bounds__(256, 4) void mega(
    const float* __restrict__ feat, const int* __restrict__ ei,
    const float* __restrict__ lw,   const float* __restrict__ att_s,
    const float* __restrict__ att_d,const float* __restrict__ bias,
    float* __restrict__ out,        __half* __restrict__ Xh,
    __half* __restrict__ Wt,        float* __restrict__ As,
    float* __restrict__ Ad,         int* __restrict__ deg,
    int* __restrict__ rowptr,       int* __restrict__ cursor,
    int* __restrict__ bsum,         int* __restrict__ csrsrc)
{
    cg::grid_group grid = cg::this_grid();
    __shared__ char smem[64 * 260 * 2];      // proj so (33.3KB); aliased by sf & scan
    const int t    = threadIdx.x;
    const int bid  = blockIdx.x;
    const int gdim = gridDim.x;
    const int gtid = bid * 256 + t;
    const int gsz  = gdim * 256;

    // ---- Phase A: zero deg --------------------------------------------------
    for (int i = gtid; i < NN; i += gsz) deg[i] = 0;
    if (gtid == 0) rowptr[NN] = NE;
    grid.sync();

    // ---- Phase B: Wt transpose + histogram ----------------------------------
    for (int i = gtid; i < IC * HC; i += gsz) {
        const int k = i >> 8, m = i & 255;
        Wt[m * IC + k] = __float2half(lw[k * HC + m]);
    }
    for (int e = gtid; e < NE; e += gsz)
        atomicAdd(&deg[ei[NE + e]], 1);
    grid.sync();

    // ---- Phase C: scan1 (49 virtual blocks) ---------------------------------
    {
        int* sh = (int*)smem;
        for (int vb = bid; vb < NSB; vb += gdim) {
            const int base = vb * 1024 + t * 4;
            int4 v = {0, 0, 0, 0};
            if (base + 3 < NN) v = *reinterpret_cast<const int4*>(deg + base);
            else {
                if (base     < NN) v.x = deg[base];
                if (base + 1 < NN) v.y = deg[base + 1];
                if (base + 2 < NN) v.z = deg[base + 2];
            }
            sh[t] = v.x + v.y + v.z + v.w;
            __syncthreads();
            for (int o = 1; o < 256; o <<= 1) {
                const int u = (t >= o) ? sh[t - o] : 0;
                __syncthreads();
                sh[t] += u;
                __syncthreads();
            }
            const int excl = t ? sh[t - 1] : 0;
            int4 e;
            e.x = excl; e.y = excl + v.x; e.z = e.y + v.y; e.w = e.z + v.z;
            if (base + 3 < NN) *reinterpret_cast<int4*>(rowptr + base) = e;
            else {
                if (base     < NN) rowptr[base]     = e.x;
                if (base + 1 < NN) rowptr[base + 1] = e.y;
                if (base + 2 < NN) rowptr[base + 2] = e.z;
            }
            if (t == 255) bsum[vb] = sh[255];
            __syncthreads();
        }
    }
    grid.sync();

    // ---- Phase D: apply chunk offsets (wave-reduce), write cursor ------------
    for (int vb = bid; vb < NSB; vb += gdim) {
        const int l = t & 63;
        int v = (l < vb) ? bsum[l] : 0;          // vb <= 48 < 64, bsum[l] valid
#pragma unroll
        for (int o = 32; o; o >>= 1) v += __shfl_xor(v, o);
        const int off  = v;                       // exclusive prefix, all lanes
        const int base = vb * 1024 + t * 4;
#pragma unroll
        for (int i = 0; i < 4; ++i) {
            const int idx = base + i;
            if (idx < NN) {
                const int r = rowptr[idx] + off;
                rowptr[idx] = r;
                cursor[idx] = r;
            }
        }
    }
    grid.sync();

    // ---- Phase E: proj MFMA (tile per block) || fill ------------------------
    for (int tile = bid; tile < NT; tile += gdim) {
        _Float16* sf = (_Float16*)smem;          // 16KB region (aliases so)
        _Float16* so = (_Float16*)smem;          // 33.3KB, used after barrier
        const int w  = t >> 6;
        const int l  = t & 63;
        const int n0 = tile * 64;

        {   // cooperative fp32->fp16 load of 64x128 feat tile, swizzled chunks
            const int r  = t >> 2;
            const int gr = min(n0 + r, NN - 1);
            const float* src = feat + (size_t)gr * IC + (t & 3) * 32;
#pragma unroll
            for (int i = 0; i < 4; ++i) {
                const float4 f0 = *reinterpret_cast<const float4*>(src + i * 8);
                const float4 f1 = *reinterpret_cast<const float4*>(src + i * 8 + 4);
                f16x8 hv;
                hv[0] = (_Float16)f0.x; hv[1] = (_Float16)f0.y;
                hv[2] = (_Float16)f0.z; hv[3] = (_Float16)f0.w;
                hv[4] = (_Float16)f1.x; hv[5] = (_Float16)f1.y;
                hv[6] = (_Float16)f1.z; hv[7] = (_Float16)f1.w;
                const int cc = (t & 3) * 4 + i;
                *reinterpret_cast<f16x8*>(&sf[(r * 16 + (cc ^ (r & 7))) * 8]) = hv;
            }
        }
        __syncthreads();

        const int lhi = l >> 4, llo = l & 15;
        f32x4 acc[4][4] = {};   // [mg(channel)][ng(node)]

#pragma unroll
        for (int ks = 0; ks < 4; ++ks) {
            f16x8 a[4], b[4];
#pragma unroll
            for (int mg = 0; mg < 4; ++mg) {
                const int row = w * 64 + mg * 16 + llo;        // channel
                a[mg] = *reinterpret_cast<const f16x8*>(
                    Wt + (size_t)row * IC + ks * 32 + lhi * 8);
            }
#pragma unroll
            for (int ng = 0; ng < 4; ++ng) {
                const int rr = ng * 16 + llo;                  // node in tile
                const int cc = ks * 4 + lhi;
                b[ng] = *reinterpret_cast<const f16x8*>(
                    &sf[(rr * 16 + (cc ^ (rr & 7))) * 8]);
            }
#pragma unroll
            for (int mg = 0; mg < 4; ++mg)
#pragma unroll
                for (int ng = 0; ng < 4; ++ng)
                    acc[mg][ng] = __builtin_amdgcn_mfma_f32_16x16x32_f16(
                        a[mg], b[ng], acc[mg][ng], 0, 0, 0);
        }
        __syncthreads();   // all sf reads done before so writes (aliased)

        float4 avs[4], avd[4];
#pragma unroll
        for (int mg = 0; mg < 4; ++mg) {
            const int ch = w * 64 + mg * 16 + 4 * lhi;
            avs[mg] = *reinterpret_cast<const float4*>(att_s + ch);
            avd[mg] = *reinterpret_cast<const float4*>(att_d + ch);
        }

#pragma unroll
        for (int ng = 0; ng < 4; ++ng) {
            const int n = n0 + ng * 16 + llo;
            float ps = 0.f, pd = 0.f;
#pragma unroll
            for (int mg = 0; mg < 4; ++mg) {
                const f32x4 v = acc[mg][ng];
                ps += v[0] * avs[mg].x + v[1] * avs[mg].y
                    + v[2] * avs[mg].z + v[3] * avs[mg].w;
                pd += v[0] * avd[mg].x + v[1] * avd[mg].y
                    + v[2] * avd[mg].z + v[3] * avd[mg].w;
                f16x4 pk;
                pk[0] = (_Float16)v[0]; pk[1] = (_Float16)v[1];
                pk[2] = (_Float16)v[2]; pk[3] = (_Float16)v[3];
                *reinterpret_cast<f16x4*>(
                    &so[(ng * 16 + llo) * 260 + w * 64 + mg * 16 + 4 * lhi]) = pk;
            }
            ps += __shfl_xor(ps, 16); ps += __shfl_xor(ps, 32);
            pd += __shfl_xor(pd, 16); pd += __shfl_xor(pd, 32);
            if (lhi == 0 && n < NN) {
                As[n * 4 + w] = ps;
                Ad[n * 4 + w] = pd;
            }
        }
        __syncthreads();

#pragma unroll
        for (int rr = 0; rr < 16; ++rr) {
            const int r = w * 16 + rr;
            const int n = n0 + r;
            if (n < NN)
                *reinterpret_cast<f16x4*>(&Xh[(size_t)n * HC + 4 * l]) =
                    *reinterpret_cast<const f16x4*>(&so[r * 260 + 4 * l]);
        }
        __syncthreads();   // so reads done before next tile's sf writes
    }

    // fill CSR (independent of proj)
    for (int e = gtid; e < NE; e += gsz) {
        const int s = ei[e];
        const int d = ei[NE + e];
        csrsrc[atomicAdd(&cursor[d], 1)] = s;
    }
    grid.sync();

    // ---- Phase F: gather, one wave per dst node ------------------------------
    {
        const int widx = t >> 6;
        const int lane = t & 63;
        const int h    = lane >> 4;
        const float4 b4 = *reinterpret_cast<const float4*>(&bias[4 * (lane & 15)]);

        for (int w = bid * 4 + widx; w < NN; w += gdim * 4) {
            const int beg = rowptr[w];
            const int end = rowptr[w + 1];
            const float adh = Ad[w * 4 + h];
            float4 acc;
            float den;

            {   // inline self-loop (always present)
                float lg = As[w * 4 + h] + adh;
                lg = lg > 0.f ? lg : 0.2f * lg;
                const float ex = __expf(lg);
                den = ex;
                const float2 xw = *reinterpret_cast<const float2*>(
                    Xh + (size_t)w * HC + 4 * lane);
                const __half2* p = reinterpret_cast<const __half2*>(&xw);
                const float2 lo = __half22float2(p[0]);
                const float2 hi = __half22float2(p[1]);
                acc.x = ex * lo.x; acc.y = ex * lo.y;
                acc.z = ex * hi.x; acc.w = ex * hi.y;
            }

            for (int j = beg; j < end; j += 8) {
                int s[8]; float a[8]; float2 x[8];
#pragma unroll
                for (int i = 0; i < 8; ++i) {
                    const int jj = j + i;
                    s[i] = csrsrc[jj < end ? jj : end - 1];   // clamp: dup = cache hit
                }
#pragma unroll
                for (int i = 0; i < 8; ++i) a[i] = As[s[i] * 4 + h];
#pragma unroll
                for (int i = 0; i < 8; ++i)
                    x[i] = *reinterpret_cast<const float2*>(
                        Xh + (size_t)s[i] * HC + 4 * lane);
#pragma unroll
                for (int i = 0; i < 8; ++i) {
                    float lg = a[i] + adh;
                    lg = lg > 0.f ? lg : 0.2f * lg;
                    const float ex = (i == 0 || j + i < end) ? __expf(lg) : 0.f;
                    den += ex;
                    const __half2* p = reinterpret_cast<const __half2*>(&x[i]);
                    const float2 lo = __half22float2(p[0]);
                    const float2 hi = __half22float2(p[1]);
                    acc.x = fmaf(ex, lo.x, acc.x); acc.y = fmaf(ex, lo.y, acc.y);
                    acc.z = fmaf(ex, hi.x, acc.z); acc.w = fmaf(ex, hi.y, acc.w);
                }
            }

            const float inv = 0.25f * __frcp_rn(den);
            acc.x *= inv; acc.y *= inv; acc.z *= inv; acc.w *= inv;

            acc.x += __shfl_xor(acc.x, 16); acc.x += __shfl_xor(acc.x, 32);
            acc.y += __shfl_xor(acc.y, 16); acc.y += __shfl_xor(acc.y, 32);
            acc.z += __shfl_xor(acc.z, 16); acc.z += __shfl_xor(acc.z, 32);
            acc.w += __shfl_xor(acc.w, 16); acc.w += __shfl_xor(acc.w, 32);

            if (lane < 16) {
                float4 o;
                o.x = acc.x + b4.x; o.y = acc.y + b4.y;
                o.z = acc.z + b4.z; o.w = acc.w + b4.w;
                *reinterpret_cast<float4*>(&out[(size_t)w * OC + 4 * lane]) = o;
            }
        }
    }
}

extern "C" void kernel_launch(void* const* d_in, const int* in_sizes, int n_in,
                              void* d_out, int out_size, void* d_ws, size_t ws_size,
                              hipStream_t stream)
{
    const float* feat = (const float*)d_in[0];
    const int*   ei   = (const int*)d_in[1];
    const float* lw   = (const float*)d_in[2];
    const float* as   = (const float*)d_in[3];
    const float* ad   = (const float*)d_in[4];
    const float* bias = (const float*)d_in[5];
    float* out = (float*)d_out;

    char* ws = (char*)d_ws;
    __half* Xh     = (__half*)ws;  ws += (size_t)NN * HC * 2;
    __half* Wt     = (__half*)ws;  ws += (size_t)HC * IC * 2;
    float*  Asrc   = (float*)ws;   ws += (size_t)NN * 4 * 4;
    float*  Adst   = (float*)ws;   ws += (size_t)NN * 4 * 4;
    int*    deg    = (int*)ws;     ws += (size_t)NN * 4;
    int*    rowptr = (int*)ws;     ws += (size_t)(NN + 1) * 4;
    int*    cursor = (int*)ws;     ws += (size_t)NN * 4;
    int*    bsum   = (int*)ws;     ws += (size_t)64 * 4;
    int*    csrsrc = (int*)ws;     ws += (size_t)NE * 4;

    int nb = 0;
    (void)hipOccupancyMaxActiveBlocksPerMultiprocessor(&nb, mega, 256, 0);
    if (nb < 1) nb = 1;
    if (nb > 8) nb = 8;
    const int grid = nb * 256;                 // 256 CUs on MI355X

    void* args[] = {
        (void*)&feat, (void*)&ei, (void*)&lw, (void*)&as, (void*)&ad,
        (void*)&bias, (void*)&out, (void*)&Xh, (void*)&Wt, (void*)&Asrc,
        (void*)&Adst, (void*)&deg, (void*)&rowptr, (void*)&cursor,
        (void*)&bsum, (void*)&csrsrc
    };
    (void)hipLaunchCooperativeKernel((const void*)mega, dim3(grid), dim3(256),
                                     args, 0u, stream);
}

// Round 11
// 177.921 us; speedup vs baseline: 2.6486x; 2.6486x over previous
//
#include <hip/hip_runtime.h>
#include <hip/hip_fp16.h>

typedef _Float16 f16x8 __attribute__((ext_vector_type(8)));
typedef _Float16 f16x4 __attribute__((ext_vector_type(4)));
typedef float    f32x4 __attribute__((ext_vector_type(4)));

constexpr int NN = 50000;        // nodes
constexpr int NE = 800000;       // real edges (self-loops handled inline)
constexpr int IC = 128;          // in channels
constexpr int HC = 256;          // heads * out_ch
constexpr int OC = 64;           // out channels

// ---------------------------------------------------------------------------
// Fused prep: blocks 0..127 transpose lin_w -> Wt fp16; remaining blocks
// histogram dst over the 800K real edges.
// ---------------------------------------------------------------------------
__global__ __launch_bounds__(256) void prep_hist(
    const float* __restrict__ w, __half* __restrict__ wt,
    const int* __restrict__ ei, int* __restrict__ deg)
{
    if (blockIdx.x < IC) {
        const int k = blockIdx.x;
        const int m = threadIdx.x;
        wt[m * IC + k] = __float2half(w[k * HC + m]);
        return;
    }
    const int e = (blockIdx.x - IC) * 256 + threadIdx.x;
    if (e >= NE) return;
    atomicAdd(&deg[ei[NE + e]], 1);
}

// ---------------------------------------------------------------------------
// Proj via MFMA + fused per-head logits. Single 33.3KB LDS buffer: input tile
// (16KB) is dead after the MFMA loop, so the output stage reuses it (barrier
// between). 4 blocks/CU (was 3 with separate buffers).
// ---------------------------------------------------------------------------
__global__ __launch_bounds__(256) void proj_mfma(
    const float* __restrict__ feat, const __half* __restrict__ wt,
    const float* __restrict__ att_s, const float* __restrict__ att_d,
    __half* __restrict__ Xh, float* __restrict__ As, float* __restrict__ Ad)
{
    __shared__ _Float16 smem[64 * 260];      // sf (first 16KB) then so (full)
    _Float16* sf = smem;
    _Float16* so = smem;
    const int t  = threadIdx.x;
    const int w  = t >> 6;
    const int l  = t & 63;
    const int n0 = blockIdx.x * 64;

    {   // cooperative fp32->fp16 load of 64x128 feat tile, swizzled 16B chunks
        const int r  = t >> 2;
        const int gr = min(n0 + r, NN - 1);
        const float* src = feat + (size_t)gr * IC + (t & 3) * 32;
#pragma unroll
        for (int i = 0; i < 4; ++i) {
            const float4 f0 = *reinterpret_cast<const float4*>(src + i * 8);
            const float4 f1 = *reinterpret_cast<const float4*>(src + i * 8 + 4);
            f16x8 hv;
            hv[0] = (_Float16)f0.x; hv[1] = (_Float16)f0.y;
            hv[2] = (_Float16)f0.z; hv[3] = (_Float16)f0.w;
            hv[4] = (_Float16)f1.x; hv[5] = (_Float16)f1.y;
            hv[6] = (_Float16)f1.z; hv[7] = (_Float16)f1.w;
            const int cc = (t & 3) * 4 + i;
            *reinterpret_cast<f16x8*>(&sf[(r * 16 + (cc ^ (r & 7))) * 8]) = hv;
        }
    }
    __syncthreads();

    const int lhi = l >> 4, llo = l & 15;
    f32x4 acc[4][4] = {};   // [mg(channel)][ng(node)]

#pragma unroll
    for (int ks = 0; ks < 4; ++ks) {
        f16x8 a[4], b[4];
#pragma unroll
        for (int mg = 0; mg < 4; ++mg) {
            const int row = w * 64 + mg * 16 + llo;            // channel
            a[mg] = *reinterpret_cast<const f16x8*>(
                wt + (size_t)row * IC + ks * 32 + lhi * 8);
        }
#pragma unroll
        for (int ng = 0; ng < 4; ++ng) {
            const int rr = ng * 16 + llo;                      // node in tile
            const int cc = ks * 4 + lhi;
            b[ng] = *reinterpret_cast<const f16x8*>(
                &sf[(rr * 16 + (cc ^ (rr & 7))) * 8]);
        }
#pragma unroll
        for (int mg = 0; mg < 4; ++mg)
#pragma unroll
            for (int ng = 0; ng < 4; ++ng)
                acc[mg][ng] = __builtin_amdgcn_mfma_f32_16x16x32_f16(
                    a[mg], b[ng], acc[mg][ng], 0, 0, 0);
    }

    float4 avs[4], avd[4];
#pragma unroll
    for (int mg = 0; mg < 4; ++mg) {
        const int ch = w * 64 + mg * 16 + 4 * lhi;
        avs[mg] = *reinterpret_cast<const float4*>(att_s + ch);
        avd[mg] = *reinterpret_cast<const float4*>(att_d + ch);
    }
    __syncthreads();   // sf reads complete before so overwrites (aliased)

#pragma unroll
    for (int ng = 0; ng < 4; ++ng) {
        const int n = n0 + ng * 16 + llo;
        float ps = 0.f, pd = 0.f;
#pragma unroll
        for (int mg = 0; mg < 4; ++mg) {
            const f32x4 v = acc[mg][ng];
            ps += v[0] * avs[mg].x + v[1] * avs[mg].y
                + v[2] * avs[mg].z + v[3] * avs[mg].w;
            pd += v[0] * avd[mg].x + v[1] * avd[mg].y
                + v[2] * avd[mg].z + v[3] * avd[mg].w;
            f16x4 pk;
            pk[0] = (_Float16)v[0]; pk[1] = (_Float16)v[1];
            pk[2] = (_Float16)v[2]; pk[3] = (_Float16)v[3];
            *reinterpret_cast<f16x4*>(
                &so[(ng * 16 + llo) * 260 + w * 64 + mg * 16 + 4 * lhi]) = pk;
        }
        ps += __shfl_xor(ps, 16); ps += __shfl_xor(ps, 32);
        pd += __shfl_xor(pd, 16); pd += __shfl_xor(pd, 32);
        if (lhi == 0 && n < NN) {
            As[n * 4 + w] = ps;
            Ad[n * 4 + w] = pd;
        }
    }
    __syncthreads();

    // coalesced store: half-wave per 512B row, 16B/lane, 8 iterations
#pragma unroll
    for (int rr = 0; rr < 8; ++rr) {
        const int r = w * 16 + rr * 2 + (l >> 5);
        const int n = n0 + r;
        if (n < NN)
            *reinterpret_cast<f16x8*>(&Xh[(size_t)n * HC + 8 * (l & 31)]) =
                *reinterpret_cast<const f16x8*>(&so[r * 260 + 8 * (l & 31)]);
    }
}

// ---------------------------------------------------------------------------
// Hierarchical scan over deg (NN entries), then fill (real edges only)
// ---------------------------------------------------------------------------
__global__ __launch_bounds__(256) void scan1(
    const int* __restrict__ deg, int* __restrict__ rowptr, int* __restrict__ bsum)
{
    __shared__ int sh[256];
    const int t = threadIdx.x;
    const int base = blockIdx.x * 1024 + t * 4;
    int4 v = {0, 0, 0, 0};
    if (base + 3 < NN) v = *reinterpret_cast<const int4*>(deg + base);
    else {
        if (base     < NN) v.x = deg[base];
        if (base + 1 < NN) v.y = deg[base + 1];
        if (base + 2 < NN) v.z = deg[base + 2];
    }
    sh[t] = v.x + v.y + v.z + v.w;
    __syncthreads();
    for (int o = 1; o < 256; o <<= 1) {
        const int u = (t >= o) ? sh[t - o] : 0;
        __syncthreads();
        sh[t] += u;
        __syncthreads();
    }
    const int excl = t ? sh[t - 1] : 0;
    int4 e;
    e.x = excl; e.y = excl + v.x; e.z = e.y + v.y; e.w = e.z + v.z;
    if (base + 3 < NN) *reinterpret_cast<int4*>(rowptr + base) = e;
    else {
        if (base     < NN) rowptr[base]     = e.x;
        if (base + 1 < NN) rowptr[base + 1] = e.y;
        if (base + 2 < NN) rowptr[base + 2] = e.z;
    }
    if (t == 255) bsum[blockIdx.x] = sh[255];
}

__global__ void scan2(int* __restrict__ bsum, int* __restrict__ rowptr_end, int nb)
{
    const int t = threadIdx.x;   // 64
    const int v = (t < nb) ? bsum[t] : 0;
    int inc = v;
#pragma unroll
    for (int o = 1; o < 64; o <<= 1) {
        const int u = __shfl_up(inc, o);
        if (t >= o) inc += u;
    }
    if (t < nb) bsum[t] = inc - v;            // exclusive block offset
    if (t == 63) rowptr_end[0] = inc;         // total = NE
}

__global__ __launch_bounds__(256) void scan3(
    int* __restrict__ rowptr, const int* __restrict__ bsum, int* __restrict__ cursor)
{
    const int off  = bsum[blockIdx.x];
    const int base = blockIdx.x * 1024 + threadIdx.x * 4;
#pragma unroll
    for (int i = 0; i < 4; ++i) {
        const int idx = base + i;
        if (idx < NN) {
            const int r = rowptr[idx] + off;
            rowptr[idx] = r;
            cursor[idx] = r;
        }
    }
}

__global__ __launch_bounds__(256) void fill_kernel(
    const int* __restrict__ ei, int* __restrict__ cursor, int* __restrict__ csr_src)
{
    const int e = blockIdx.x * 256 + threadIdx.x;
    if (e >= NE) return;
    const int s = ei[e];
    const int d = ei[NE + e];
    csr_src[atomicAdd(&cursor[d], 1)] = s;
}

// ---------------------------------------------------------------------------
// Gather: one wave per dst node; lane group h = lane>>4 handles only head h.
// Self-loop inline; real edges batch-4 with clamped tail (dup loads = cache
// hits, masked by ex=0). 12 independent loads in flight per iteration.
// ---------------------------------------------------------------------------
__global__ __launch_bounds__(256) void gather_kernel(
    const int* __restrict__ rowptr, const int* __restrict__ csr_src,
    const float* __restrict__ As, const float* __restrict__ Ad,
    const __half* __restrict__ Xh, const float* __restrict__ bias,
    float* __restrict__ out)
{
    const int gid  = blockIdx.x * 256 + threadIdx.x;
    const int w    = gid >> 6;
    const int lane = gid & 63;
    if (w >= NN) return;

    const int beg = rowptr[w];
    const int end = rowptr[w + 1];
    const int h   = lane >> 4;

    const float adh = Ad[w * 4 + h];
    float4 acc;
    float den;

    {   // inline self-loop (always present per reference)
        float lg = As[w * 4 + h] + adh;
        lg = lg > 0.f ? lg : 0.2f * lg;
        const float ex = __expf(lg);
        den = ex;
        const float2 xw = *reinterpret_cast<const float2*>(
            Xh + (size_t)w * HC + 4 * lane);
        const __half2* p = reinterpret_cast<const __half2*>(&xw);
        const float2 lo = __half22float2(p[0]);
        const float2 hi = __half22float2(p[1]);
        acc.x = ex * lo.x; acc.y = ex * lo.y;
        acc.z = ex * hi.x; acc.w = ex * hi.y;
    }

    for (int j = beg; j < end; j += 4) {
        int s[4]; float a[4]; float2 x[4];
#pragma unroll
        for (int i = 0; i < 4; ++i) {
            const int jj = j + i;
            s[i] = csr_src[jj < end ? jj : end - 1];   // clamp: dup = cache hit
        }
#pragma unroll
        for (int i = 0; i < 4; ++i) a[i] = As[s[i] * 4 + h];
#pragma unroll
        for (int i = 0; i < 4; ++i)
            x[i] = *reinterpret_cast<const float2*>(
                Xh + (size_t)s[i] * HC + 4 * lane);
#pragma unroll
        for (int i = 0; i < 4; ++i) {
            float lg = a[i] + adh;
            lg = lg > 0.f ? lg : 0.2f * lg;
            const float ex = (i == 0 || j + i < end) ? __expf(lg) : 0.f;
            den += ex;
            const __half2* p = reinterpret_cast<const __half2*>(&x[i]);
            const float2 lo = __half22float2(p[0]);
            const float2 hi = __half22float2(p[1]);
            acc.x = fmaf(ex, lo.x, acc.x); acc.y = fmaf(ex, lo.y, acc.y);
            acc.z = fmaf(ex, hi.x, acc.z); acc.w = fmaf(ex, hi.y, acc.w);
        }
    }

    const float inv = 0.25f * __frcp_rn(den);
    acc.x *= inv; acc.y *= inv; acc.z *= inv; acc.w *= inv;

    acc.x += __shfl_xor(acc.x, 16); acc.x += __shfl_xor(acc.x, 32);
    acc.y += __shfl_xor(acc.y, 16); acc.y += __shfl_xor(acc.y, 32);
    acc.z += __shfl_xor(acc.z, 16); acc.z += __shfl_xor(acc.z, 32);
    acc.w += __shfl_xor(acc.w, 16); acc.w += __shfl_xor(acc.w, 32);

    if (lane < 16) {
        const float4 b = *reinterpret_cast<const float4*>(&bias[4 * lane]);
        float4 o;
        o.x = acc.x + b.x; o.y = acc.y + b.y;
        o.z = acc.z + b.z; o.w = acc.w + b.w;
        *reinterpret_cast<float4*>(&out[(size_t)w * OC + 4 * lane]) = o;
    }
}

extern "C" void kernel_launch(void* const* d_in, const int* in_sizes, int n_in,
                              void* d_out, int out_size, void* d_ws, size_t ws_size,
                              hipStream_t stream)
{
    const float* feat = (const float*)d_in[0];
    const int*   ei   = (const int*)d_in[1];
    const float* lw   = (const float*)d_in[2];
    const float* as   = (const float*)d_in[3];
    const float* ad   = (const float*)d_in[4];
    const float* bias = (const float*)d_in[5];
    float* out = (float*)d_out;

    constexpr int NSB = (NN + 1023) / 1024;   // 49 scan blocks

    char* ws = (char*)d_ws;
    __half* Xh     = (__half*)ws;  ws += (size_t)NN * HC * 2;
    __half* Wt     = (__half*)ws;  ws += (size_t)HC * IC * 2;
    float*  Asrc   = (float*)ws;   ws += (size_t)NN * 4 * 4;
    float*  Adst   = (float*)ws;   ws += (size_t)NN * 4 * 4;
    int*    deg    = (int*)ws;     ws += (size_t)NN * 4;      // zeroed
    int*    rowptr = (int*)ws;     ws += (size_t)(NN + 1) * 4;
    int*    cursor = (int*)ws;     ws += (size_t)NN * 4;
    int*    bsum   = (int*)ws;     ws += (size_t)64 * 4;
    int*    csrsrc = (int*)ws;     ws += (size_t)NE * 4;

    (void)hipMemsetAsync(deg, 0, sizeof(int) * (size_t)NN, stream);

    prep_hist<<<IC + (NE + 255) / 256, 256, 0, stream>>>(lw, Wt, ei, deg);
    proj_mfma<<<(NN + 63) / 64, 256, 0, stream>>>(feat, Wt, as, ad, Xh, Asrc, Adst);
    scan1<<<NSB, 256, 0, stream>>>(deg, rowptr, bsum);
    scan2<<<1, 64, 0, stream>>>(bsum, rowptr + NN, NSB);
    scan3<<<NSB, 256, 0, stream>>>(rowptr, bsum, cursor);
    fill_kernel<<<(NE + 255) / 256, 256, 0, stream>>>(ei, cursor, csrsrc);
    gather_kernel<<<(NN * 64 + 255) / 256, 256, 0, stream>>>(
        rowptr, csrsrc, Asrc, Adst, Xh, bias, out);
}